// Round 2
// baseline (69.926 us; speedup 1.0000x reference)
//
#include <hip/hip_runtime.h>

// Problem shape (fixed by reference setup_inputs):
//   out:   (N=8, K=128, H=256, W=256) f32 logits
//   label: (N=8, 3, H, W) f32
//   centroids: (K=128, 3) f32
// Output: scalar f32 loss.

constexpr int K_CL   = 128;
constexpr int NIMG   = 8;
constexpr int HW     = 256 * 256;
constexpr int PPT    = 4;            // pixels per thread (float4)
constexpr int BLOCK  = 256;
constexpr int TOTAL_PIX = NIMG * HW;                      // 524288
constexpr int NBLOCKS   = TOTAL_PIX / (PPT * BLOCK);      // 512
constexpr float IGNORE_F = 255.0f;

__global__ __launch_bounds__(BLOCK) void cce_main(
    const float* __restrict__ logits,
    const float* __restrict__ label,
    const float* __restrict__ cent,
    float* __restrict__ partial_num,
    float* __restrict__ partial_cnt)
{
    // Stage centroids (x,y,z,|c|^2) in LDS; reads are wave-uniform broadcasts.
    __shared__ float sc[K_CL][4];
    const int t = threadIdx.x;
    if (t < K_CL) {
        float x = cent[t * 3 + 0];
        float y = cent[t * 3 + 1];
        float z = cent[t * 3 + 2];
        sc[t][0] = x; sc[t][1] = y; sc[t][2] = z;
        sc[t][3] = x * x + y * y + z * z;
    }
    __syncthreads();

    const long tid = (long)blockIdx.x * BLOCK + t;
    const long P   = tid * PPT;                 // global pixel base (PPT-aligned, within one image)
    const int  n   = (int)(P / HW);
    const int  p   = (int)(P % HW);

    // ---- label loads (3 channels x 4 pixels, coalesced float4) ----
    const float* lb = label + ((long)n * 3) * HW + p;
    const float4 l0 = *(const float4*)(lb);
    const float4 l1 = *(const float4*)(lb + HW);
    const float4 l2 = *(const float4*)(lb + 2 * HW);
    float LX[4] = { l0.x, l0.y, l0.z, l0.w };
    float LY[4] = { l1.x, l1.y, l1.z, l1.w };
    float LZ[4] = { l2.x, l2.y, l2.z, l2.w };

    // ---- centroid argmin (matches reference d2 = |lab|^2 - 2*dot + |c|^2) ----
    float slab[4], best[4];
    int   idx[4];
#pragma unroll
    for (int j = 0; j < 4; ++j)
        slab[j] = LX[j] * LX[j] + LY[j] * LY[j] + LZ[j] * LZ[j];
    {
        const float cx = sc[0][0], cy = sc[0][1], cz = sc[0][2], c2 = sc[0][3];
#pragma unroll
        for (int j = 0; j < 4; ++j) {
            float dot = LX[j] * cx + LY[j] * cy + LZ[j] * cz;
            best[j] = slab[j] - 2.0f * dot + c2;
            idx[j]  = 0;
        }
    }
#pragma unroll 4
    for (int k = 1; k < K_CL; ++k) {
        const float cx = sc[k][0], cy = sc[k][1], cz = sc[k][2], c2 = sc[k][3];
#pragma unroll
        for (int j = 0; j < 4; ++j) {
            float dot = LX[j] * cx + LY[j] * cy + LZ[j] * cz;
            float d   = slab[j] - 2.0f * dot + c2;
            if (d < best[j]) { best[j] = d; idx[j] = k; }   // strict < == first-occurrence argmin
        }
    }

    // ---- single pass over K logits: online softmax + capture picked logit ----
    const float* ob = logits + ((long)n * K_CL) * HW + p;
    const float4 v0 = *(const float4*)ob;
    float V0[4] = { v0.x, v0.y, v0.z, v0.w };
    float m[4], s[4], vsel[4];
#pragma unroll
    for (int j = 0; j < 4; ++j) {
        m[j] = V0[j];
        s[j] = 1.0f;
        vsel[j] = (idx[j] == 0) ? V0[j] : 0.0f;
    }
#pragma unroll 4
    for (int k = 1; k < K_CL; ++k) {
        const float4 v = *(const float4*)(ob + (long)k * HW);
        float W4[4] = { v.x, v.y, v.z, v.w };
#pragma unroll
        for (int j = 0; j < 4; ++j) {
            float vj = W4[j];
            float nm = fmaxf(m[j], vj);
            s[j] = s[j] * __expf(m[j] - nm) + __expf(vj - nm);
            m[j] = nm;
            vsel[j] = (k == idx[j]) ? vj : vsel[j];
        }
    }

    // ---- per-pixel loss contribution (valid mask) ----
    float lsum = 0.0f, lcnt = 0.0f;
#pragma unroll
    for (int j = 0; j < 4; ++j) {
        bool ignore = (LX[j] == IGNORE_F) || (LY[j] == IGNORE_F) || (LZ[j] == IGNORE_F);
        float logp = vsel[j] - m[j] - __logf(s[j]);
        if (!ignore) { lsum += logp; lcnt += 1.0f; }
    }

    // ---- wave (64-lane) shuffle reduce, then cross-wave via LDS ----
#pragma unroll
    for (int off = 32; off > 0; off >>= 1) {
        lsum += __shfl_down(lsum, off);
        lcnt += __shfl_down(lcnt, off);
    }
    __shared__ float wsum[BLOCK / 64], wcnt[BLOCK / 64];
    const int wave = t >> 6, lane = t & 63;
    if (lane == 0) { wsum[wave] = lsum; wcnt[wave] = lcnt; }
    __syncthreads();
    if (t == 0) {
        float a = 0.0f, c = 0.0f;
#pragma unroll
        for (int i = 0; i < BLOCK / 64; ++i) { a += wsum[i]; c += wcnt[i]; }
        partial_num[blockIdx.x] = a;
        partial_cnt[blockIdx.x] = c;
    }
}

// Deterministic final reduce: fixed-order strided sums in double, LDS tree.
__global__ __launch_bounds__(BLOCK) void cce_reduce(
    const float* __restrict__ partial_num,
    const float* __restrict__ partial_cnt,
    float* __restrict__ out,
    int nblocks)
{
    const int t = threadIdx.x;
    double s = 0.0, c = 0.0;
    for (int i = t; i < nblocks; i += BLOCK) {
        s += (double)partial_num[i];
        c += (double)partial_cnt[i];
    }
    __shared__ double sh_s[BLOCK], sh_c[BLOCK];
    sh_s[t] = s; sh_c[t] = c;
    __syncthreads();
    for (int off = BLOCK / 2; off > 0; off >>= 1) {
        if (t < off) { sh_s[t] += sh_s[t + off]; sh_c[t] += sh_c[t + off]; }
        __syncthreads();
    }
    if (t == 0) {
        double den = sh_c[0] > 1.0 ? sh_c[0] : 1.0;
        out[0] = (float)(-sh_s[0] / den);
    }
}

extern "C" void kernel_launch(void* const* d_in, const int* in_sizes, int n_in,
                              void* d_out, int out_size, void* d_ws, size_t ws_size,
                              hipStream_t stream)
{
    const float* logits = (const float*)d_in[0];   // (N,K,H,W)
    const float* label  = (const float*)d_in[1];   // (N,3,H,W)
    const float* cent   = (const float*)d_in[2];   // (K,3)
    float* out = (float*)d_out;

    float* partial_num = (float*)d_ws;             // NBLOCKS floats
    float* partial_cnt = partial_num + NBLOCKS;    // NBLOCKS floats

    cce_main<<<NBLOCKS, BLOCK, 0, stream>>>(logits, label, cent, partial_num, partial_cnt);
    cce_reduce<<<1, BLOCK, 0, stream>>>(partial_num, partial_cnt, out, NBLOCKS);
}

// Round 3
// 69.829 us; speedup vs baseline: 1.0014x; 1.0014x over previous
//
#include <hip/hip_runtime.h>

// Problem shape (fixed by reference setup_inputs):
//   out:   (N=8, K=128, H=256, W=256) f32 logits
//   label: (N=8, 3, H, W) f32
//   centroids: (K=128, 3) f32
// Output: scalar f32 loss.

constexpr int K_CL   = 128;
constexpr int NIMG   = 8;
constexpr int HW     = 256 * 256;
constexpr int PPT    = 4;            // pixels per thread (float4)
constexpr int BLOCK  = 256;
constexpr int TOTAL_PIX = NIMG * HW;                      // 524288
constexpr int NBLOCKS   = TOTAL_PIX / (PPT * BLOCK);      // 512
constexpr float IGNORE_F = 255.0f;

__global__ __launch_bounds__(BLOCK) void cce_main(
    const float* __restrict__ logits,
    const float* __restrict__ label,
    const float* __restrict__ cent,
    float* __restrict__ partial_num,
    float* __restrict__ partial_cnt)
{
    // Stage centroids (x,y,z,|c|^2) in LDS; reads are wave-uniform broadcasts.
    __shared__ float sc[K_CL][4];
    const int t = threadIdx.x;
    if (t < K_CL) {
        float x = cent[t * 3 + 0];
        float y = cent[t * 3 + 1];
        float z = cent[t * 3 + 2];
        sc[t][0] = x; sc[t][1] = y; sc[t][2] = z;
        sc[t][3] = x * x + y * y + z * z;
    }
    __syncthreads();

    const long tid = (long)blockIdx.x * BLOCK + t;
    const long P   = tid * PPT;                 // global pixel base (PPT-aligned, within one image)
    const int  n   = (int)(P / HW);
    const int  p   = (int)(P % HW);

    // ---- label loads (3 channels x 4 pixels, coalesced float4) ----
    const float* lb = label + ((long)n * 3) * HW + p;
    const float4 l0 = *(const float4*)(lb);
    const float4 l1 = *(const float4*)(lb + HW);
    const float4 l2 = *(const float4*)(lb + 2 * HW);
    float LX[4] = { l0.x, l0.y, l0.z, l0.w };
    float LY[4] = { l1.x, l1.y, l1.z, l1.w };
    float LZ[4] = { l2.x, l2.y, l2.z, l2.w };

    // ---- centroid argmin (matches reference d2 = |lab|^2 - 2*dot + |c|^2) ----
    float slab[4], best[4];
    int   idx[4];
#pragma unroll
    for (int j = 0; j < 4; ++j)
        slab[j] = LX[j] * LX[j] + LY[j] * LY[j] + LZ[j] * LZ[j];
    {
        const float cx = sc[0][0], cy = sc[0][1], cz = sc[0][2], c2 = sc[0][3];
#pragma unroll
        for (int j = 0; j < 4; ++j) {
            float dot = LX[j] * cx + LY[j] * cy + LZ[j] * cz;
            best[j] = slab[j] - 2.0f * dot + c2;
            idx[j]  = 0;
        }
    }
#pragma unroll 4
    for (int k = 1; k < K_CL; ++k) {
        const float cx = sc[k][0], cy = sc[k][1], cz = sc[k][2], c2 = sc[k][3];
#pragma unroll
        for (int j = 0; j < 4; ++j) {
            float dot = LX[j] * cx + LY[j] * cy + LZ[j] * cz;
            float d   = slab[j] - 2.0f * dot + c2;
            if (d < best[j]) { best[j] = d; idx[j] = k; }   // strict < == first-occurrence argmin
        }
    }

    // ---- single pass over K logits: online softmax + capture picked logit ----
    const float* ob = logits + ((long)n * K_CL) * HW + p;
    const float4 v0 = *(const float4*)ob;
    float V0[4] = { v0.x, v0.y, v0.z, v0.w };
    float m[4], s[4], vsel[4];
#pragma unroll
    for (int j = 0; j < 4; ++j) {
        m[j] = V0[j];
        s[j] = 1.0f;
        vsel[j] = (idx[j] == 0) ? V0[j] : 0.0f;
    }
#pragma unroll 4
    for (int k = 1; k < K_CL; ++k) {
        const float4 v = *(const float4*)(ob + (long)k * HW);
        float W4[4] = { v.x, v.y, v.z, v.w };
#pragma unroll
        for (int j = 0; j < 4; ++j) {
            float vj = W4[j];
            float nm = fmaxf(m[j], vj);
            s[j] = s[j] * __expf(m[j] - nm) + __expf(vj - nm);
            m[j] = nm;
            vsel[j] = (k == idx[j]) ? vj : vsel[j];
        }
    }

    // ---- per-pixel loss contribution (valid mask) ----
    float lsum = 0.0f, lcnt = 0.0f;
#pragma unroll
    for (int j = 0; j < 4; ++j) {
        bool ignore = (LX[j] == IGNORE_F) || (LY[j] == IGNORE_F) || (LZ[j] == IGNORE_F);
        float logp = vsel[j] - m[j] - __logf(s[j]);
        if (!ignore) { lsum += logp; lcnt += 1.0f; }
    }

    // ---- wave (64-lane) shuffle reduce, then cross-wave via LDS ----
#pragma unroll
    for (int off = 32; off > 0; off >>= 1) {
        lsum += __shfl_down(lsum, off);
        lcnt += __shfl_down(lcnt, off);
    }
    __shared__ float wsum[BLOCK / 64], wcnt[BLOCK / 64];
    const int wave = t >> 6, lane = t & 63;
    if (lane == 0) { wsum[wave] = lsum; wcnt[wave] = lcnt; }
    __syncthreads();
    if (t == 0) {
        float a = 0.0f, c = 0.0f;
#pragma unroll
        for (int i = 0; i < BLOCK / 64; ++i) { a += wsum[i]; c += wcnt[i]; }
        partial_num[blockIdx.x] = a;
        partial_cnt[blockIdx.x] = c;
    }
}

// Deterministic final reduce: fixed-order strided sums in double, LDS tree.
__global__ __launch_bounds__(BLOCK) void cce_reduce(
    const float* __restrict__ partial_num,
    const float* __restrict__ partial_cnt,
    float* __restrict__ out,
    int nblocks)
{
    const int t = threadIdx.x;
    double s = 0.0, c = 0.0;
    for (int i = t; i < nblocks; i += BLOCK) {
        s += (double)partial_num[i];
        c += (double)partial_cnt[i];
    }
    __shared__ double sh_s[BLOCK], sh_c[BLOCK];
    sh_s[t] = s; sh_c[t] = c;
    __syncthreads();
    for (int off = BLOCK / 2; off > 0; off >>= 1) {
        if (t < off) { sh_s[t] += sh_s[t + off]; sh_c[t] += sh_c[t + off]; }
        __syncthreads();
    }
    if (t == 0) {
        double den = sh_c[0] > 1.0 ? sh_c[0] : 1.0;
        out[0] = (float)(-sh_s[0] / den);
    }
}

extern "C" void kernel_launch(void* const* d_in, const int* in_sizes, int n_in,
                              void* d_out, int out_size, void* d_ws, size_t ws_size,
                              hipStream_t stream)
{
    const float* logits = (const float*)d_in[0];   // (N,K,H,W)
    const float* label  = (const float*)d_in[1];   // (N,3,H,W)
    const float* cent   = (const float*)d_in[2];   // (K,3)
    float* out = (float*)d_out;

    float* partial_num = (float*)d_ws;             // NBLOCKS floats
    float* partial_cnt = partial_num + NBLOCKS;    // NBLOCKS floats

    cce_main<<<NBLOCKS, BLOCK, 0, stream>>>(logits, label, cent, partial_num, partial_cnt);
    cce_reduce<<<1, BLOCK, 0, stream>>>(partial_num, partial_cnt, out, NBLOCKS);
}

// Round 4
// 60.818 us; speedup vs baseline: 1.1497x; 1.1482x over previous
//
#include <hip/hip_runtime.h>

// Problem shape (fixed by reference setup_inputs):
//   out:   (N=8, K=128, H=256, W=256) f32 logits
//   label: (N=8, 3, H, W) f32
//   centroids: (K=128, 3) f32
// Output: scalar f32 loss.

constexpr int K_CL   = 128;
constexpr int NIMG   = 8;
constexpr int HW     = 256 * 256;
constexpr int PPT    = 2;            // pixels per thread (float2 loads; doubles wave count vs PPT=4)
constexpr int BLOCK  = 256;
constexpr int TOTAL_PIX = NIMG * HW;                      // 524288
constexpr int NBLOCKS   = TOTAL_PIX / (PPT * BLOCK);      // 1024 -> 4 waves/SIMD
constexpr float IGNORE_F = 255.0f;

__global__ __launch_bounds__(BLOCK) void cce_main(
    const float* __restrict__ logits,
    const float* __restrict__ label,
    const float* __restrict__ cent,
    float* __restrict__ partial_num,
    float* __restrict__ partial_cnt)
{
    // Stage centroids (x,y,z,|c|^2) in LDS; reads are wave-uniform broadcasts.
    __shared__ float sc[K_CL][4];
    const int t = threadIdx.x;
    if (t < K_CL) {
        float x = cent[t * 3 + 0];
        float y = cent[t * 3 + 1];
        float z = cent[t * 3 + 2];
        sc[t][0] = x; sc[t][1] = y; sc[t][2] = z;
        sc[t][3] = x * x + y * y + z * z;
    }
    __syncthreads();

    const long tid = (long)blockIdx.x * BLOCK + t;
    const long P   = tid * PPT;                 // global pixel base (PPT-aligned, within one image)
    const int  n   = (int)(P / HW);
    const int  p   = (int)(P % HW);

    // ---- label loads (3 channels x 2 pixels, coalesced float2) ----
    const float* lb = label + ((long)n * 3) * HW + p;
    const float2 l0 = *(const float2*)(lb);
    const float2 l1 = *(const float2*)(lb + HW);
    const float2 l2 = *(const float2*)(lb + 2 * HW);
    float LX[PPT] = { l0.x, l0.y };
    float LY[PPT] = { l1.x, l1.y };
    float LZ[PPT] = { l2.x, l2.y };

    // ---- centroid argmin (matches reference d2 = |lab|^2 - 2*dot + |c|^2) ----
    float slab[PPT], best[PPT];
    int   idx[PPT];
#pragma unroll
    for (int j = 0; j < PPT; ++j)
        slab[j] = LX[j] * LX[j] + LY[j] * LY[j] + LZ[j] * LZ[j];
    {
        const float cx = sc[0][0], cy = sc[0][1], cz = sc[0][2], c2 = sc[0][3];
#pragma unroll
        for (int j = 0; j < PPT; ++j) {
            float dot = LX[j] * cx + LY[j] * cy + LZ[j] * cz;
            best[j] = slab[j] - 2.0f * dot + c2;
            idx[j]  = 0;
        }
    }
#pragma unroll 8
    for (int k = 1; k < K_CL; ++k) {
        const float cx = sc[k][0], cy = sc[k][1], cz = sc[k][2], c2 = sc[k][3];
#pragma unroll
        for (int j = 0; j < PPT; ++j) {
            float dot = LX[j] * cx + LY[j] * cy + LZ[j] * cz;
            float d   = slab[j] - 2.0f * dot + c2;
            if (d < best[j]) { best[j] = d; idx[j] = k; }   // strict < == first-occurrence argmin
        }
    }

    // ---- single pass over K logits: online softmax + capture picked logit ----
    // Single-exp update: the exp argument is always min(v,m) - max(v,m) = -|v-m|:
    //   v >  m : s = s*exp(m-v) + 1
    //   v <= m : s = s + exp(v-m)
    const float* ob = logits + ((long)n * K_CL) * HW + p;
    const float2 v0 = *(const float2*)ob;
    float V0[PPT] = { v0.x, v0.y };
    float m[PPT], s[PPT], vsel[PPT];
#pragma unroll
    for (int j = 0; j < PPT; ++j) {
        m[j] = V0[j];
        s[j] = 1.0f;
        vsel[j] = (idx[j] == 0) ? V0[j] : 0.0f;
    }
#pragma unroll 8
    for (int k = 1; k < K_CL; ++k) {
        const float2 v = *(const float2*)(ob + (long)k * HW);
        float W2[PPT] = { v.x, v.y };
#pragma unroll
        for (int j = 0; j < PPT; ++j) {
            float vj = W2[j];
            float e  = __expf(-fabsf(vj - m[j]));
            bool  up = vj > m[j];
            s[j] = up ? fmaf(s[j], e, 1.0f) : (s[j] + e);
            m[j] = fmaxf(m[j], vj);
            vsel[j] = (k == idx[j]) ? vj : vsel[j];
        }
    }

    // ---- per-pixel loss contribution (valid mask) ----
    float lsum = 0.0f, lcnt = 0.0f;
#pragma unroll
    for (int j = 0; j < PPT; ++j) {
        bool ignore = (LX[j] == IGNORE_F) || (LY[j] == IGNORE_F) || (LZ[j] == IGNORE_F);
        float logp = vsel[j] - m[j] - __logf(s[j]);
        if (!ignore) { lsum += logp; lcnt += 1.0f; }
    }

    // ---- wave (64-lane) shuffle reduce, then cross-wave via LDS ----
#pragma unroll
    for (int off = 32; off > 0; off >>= 1) {
        lsum += __shfl_down(lsum, off);
        lcnt += __shfl_down(lcnt, off);
    }
    __shared__ float wsum[BLOCK / 64], wcnt[BLOCK / 64];
    const int wave = t >> 6, lane = t & 63;
    if (lane == 0) { wsum[wave] = lsum; wcnt[wave] = lcnt; }
    __syncthreads();
    if (t == 0) {
        float a = 0.0f, c = 0.0f;
#pragma unroll
        for (int i = 0; i < BLOCK / 64; ++i) { a += wsum[i]; c += wcnt[i]; }
        partial_num[blockIdx.x] = a;
        partial_cnt[blockIdx.x] = c;
    }
}

// Deterministic final reduce: fixed-order strided sums in double, LDS tree.
__global__ __launch_bounds__(BLOCK) void cce_reduce(
    const float* __restrict__ partial_num,
    const float* __restrict__ partial_cnt,
    float* __restrict__ out,
    int nblocks)
{
    const int t = threadIdx.x;
    double s = 0.0, c = 0.0;
    for (int i = t; i < nblocks; i += BLOCK) {
        s += (double)partial_num[i];
        c += (double)partial_cnt[i];
    }
    __shared__ double sh_s[BLOCK], sh_c[BLOCK];
    sh_s[t] = s; sh_c[t] = c;
    __syncthreads();
    for (int off = BLOCK / 2; off > 0; off >>= 1) {
        if (t < off) { sh_s[t] += sh_s[t + off]; sh_c[t] += sh_c[t + off]; }
        __syncthreads();
    }
    if (t == 0) {
        double den = sh_c[0] > 1.0 ? sh_c[0] : 1.0;
        out[0] = (float)(-sh_s[0] / den);
    }
}

extern "C" void kernel_launch(void* const* d_in, const int* in_sizes, int n_in,
                              void* d_out, int out_size, void* d_ws, size_t ws_size,
                              hipStream_t stream)
{
    const float* logits = (const float*)d_in[0];   // (N,K,H,W)
    const float* label  = (const float*)d_in[1];   // (N,3,H,W)
    const float* cent   = (const float*)d_in[2];   // (K,3)
    float* out = (float*)d_out;

    float* partial_num = (float*)d_ws;             // NBLOCKS floats
    float* partial_cnt = partial_num + NBLOCKS;    // NBLOCKS floats

    cce_main<<<NBLOCKS, BLOCK, 0, stream>>>(logits, label, cent, partial_num, partial_cnt);
    cce_reduce<<<1, BLOCK, 0, stream>>>(partial_num, partial_cnt, out, NBLOCKS);
}

// Round 5
// 56.027 us; speedup vs baseline: 1.2481x; 1.0855x over previous
//
#include <hip/hip_runtime.h>
#include <math.h>

// Problem shape (fixed by reference setup_inputs):
//   out:   (N=8, K=128, H=256, W=256) f32 logits
//   label: (N=8, 3, H, W) f32
//   centroids: (K=128, 3) f32
// Output: scalar f32 loss.
//
// Roofline: 268 MB logits + 25 MB label read once -> ~42 us at the 7 TB/s
// demonstrated by the harness fills. Strategy: one pixel per thread, grid
// 2048 blocks = 8 waves/SIMD (max TLP), batch-8 loads for MLP inside the
// serial online-softmax chain.

constexpr int K_CL   = 128;
constexpr int NIMG   = 8;
constexpr int HW     = 256 * 256;
constexpr int BLOCK  = 256;
constexpr int TOTAL_PIX = NIMG * HW;             // 524288
constexpr int NBLOCKS   = TOTAL_PIX / BLOCK;     // 2048 -> 8 waves/SIMD
constexpr float IGNORE_F = 255.0f;

__global__ __launch_bounds__(BLOCK) void cce_main(
    const float* __restrict__ logits,
    const float* __restrict__ label,
    const float* __restrict__ cent,
    float* __restrict__ partial_num,
    float* __restrict__ partial_cnt)
{
    // Stage centroids (x,y,z,|c|^2) in LDS; reads are wave-uniform broadcasts.
    __shared__ float sc[K_CL][4];
    const int t = threadIdx.x;
    if (t < K_CL) {
        float x = cent[t * 3 + 0];
        float y = cent[t * 3 + 1];
        float z = cent[t * 3 + 2];
        sc[t][0] = x; sc[t][1] = y; sc[t][2] = z;
        sc[t][3] = x * x + y * y + z * z;
    }
    __syncthreads();

    const int P = blockIdx.x * BLOCK + t;        // global pixel id
    const int n = P >> 16;                       // P / HW
    const int p = P & (HW - 1);                  // P % HW

    // ---- label loads (3 channels, coalesced dword: 256B/wave/channel) ----
    const float* lb = label + ((long)n * 3) * HW + p;
    const float LX = lb[0];
    const float LY = lb[HW];
    const float LZ = lb[2 * HW];

    // ---- centroid argmin (matches reference d2 = |lab|^2 - 2*dot + |c|^2;
    //      strict < == first-occurrence argmin, same as jnp.argmin) ----
    const float slab = LX * LX + LY * LY + LZ * LZ;
    float best = INFINITY;
    int   idx  = 0;
#pragma unroll 8
    for (int k = 0; k < K_CL; ++k) {
        float dot = LX * sc[k][0] + LY * sc[k][1] + LZ * sc[k][2];
        float d   = slab - 2.0f * dot + sc[k][3];
        if (d < best) { best = d; idx = k; }
    }

    // ---- single pass over K logits: online softmax + capture picked logit.
    // m=-inf, s=0 makes k=0 uniform: e=exp(-inf)=0, up=true -> s=fma(0,0,1)=1.
    // Single-exp update (arg is always min(v,m)-max(v,m) = -|v-m|):
    //   v >  m : s = s*e + 1
    //   v <= m : s = s + e
    const float* ob = logits + ((long)n * K_CL) * HW + p;
    float m = -INFINITY, s = 0.0f, vsel = 0.0f;
#pragma unroll 2
    for (int kb = 0; kb < K_CL; kb += 8) {
        float w[8];
#pragma unroll
        for (int u = 0; u < 8; ++u)                // 8 independent loads in flight
            w[u] = ob[(long)(kb + u) * HW];
#pragma unroll
        for (int u = 0; u < 8; ++u) {
            const int   k  = kb + u;
            const float vj = w[u];
            float e  = __expf(-fabsf(vj - m));
            bool  up = vj > m;
            s = up ? fmaf(s, e, 1.0f) : (s + e);
            m = fmaxf(m, vj);
            vsel = (k == idx) ? vj : vsel;
        }
    }

    // ---- per-pixel loss contribution (valid mask) ----
    const bool ignore = (LX == IGNORE_F) || (LY == IGNORE_F) || (LZ == IGNORE_F);
    float lsum = 0.0f, lcnt = 0.0f;
    if (!ignore) {
        lsum = vsel - m - __logf(s);
        lcnt = 1.0f;
    }

    // ---- wave (64-lane) shuffle reduce, then cross-wave via LDS ----
#pragma unroll
    for (int off = 32; off > 0; off >>= 1) {
        lsum += __shfl_down(lsum, off);
        lcnt += __shfl_down(lcnt, off);
    }
    __shared__ float wsum[BLOCK / 64], wcnt[BLOCK / 64];
    const int wave = t >> 6, lane = t & 63;
    if (lane == 0) { wsum[wave] = lsum; wcnt[wave] = lcnt; }
    __syncthreads();
    if (t == 0) {
        float a = 0.0f, c = 0.0f;
#pragma unroll
        for (int i = 0; i < BLOCK / 64; ++i) { a += wsum[i]; c += wcnt[i]; }
        partial_num[blockIdx.x] = a;
        partial_cnt[blockIdx.x] = c;
    }
}

// Deterministic final reduce: fixed-order strided sums in double, LDS tree.
__global__ __launch_bounds__(BLOCK) void cce_reduce(
    const float* __restrict__ partial_num,
    const float* __restrict__ partial_cnt,
    float* __restrict__ out,
    int nblocks)
{
    const int t = threadIdx.x;
    double s = 0.0, c = 0.0;
    for (int i = t; i < nblocks; i += BLOCK) {
        s += (double)partial_num[i];
        c += (double)partial_cnt[i];
    }
    __shared__ double sh_s[BLOCK], sh_c[BLOCK];
    sh_s[t] = s; sh_c[t] = c;
    __syncthreads();
    for (int off = BLOCK / 2; off > 0; off >>= 1) {
        if (t < off) { sh_s[t] += sh_s[t + off]; sh_c[t] += sh_c[t + off]; }
        __syncthreads();
    }
    if (t == 0) {
        double den = sh_c[0] > 1.0 ? sh_c[0] : 1.0;
        out[0] = (float)(-sh_s[0] / den);
    }
}

extern "C" void kernel_launch(void* const* d_in, const int* in_sizes, int n_in,
                              void* d_out, int out_size, void* d_ws, size_t ws_size,
                              hipStream_t stream)
{
    const float* logits = (const float*)d_in[0];   // (N,K,H,W)
    const float* label  = (const float*)d_in[1];   // (N,3,H,W)
    const float* cent   = (const float*)d_in[2];   // (K,3)
    float* out = (float*)d_out;

    float* partial_num = (float*)d_ws;             // NBLOCKS floats
    float* partial_cnt = partial_num + NBLOCKS;    // NBLOCKS floats

    cce_main<<<NBLOCKS, BLOCK, 0, stream>>>(logits, label, cent, partial_num, partial_cnt);
    cce_reduce<<<1, BLOCK, 0, stream>>>(partial_num, partial_cnt, out, NBLOCKS);
}